// Round 1
// baseline (546.157 us; speedup 1.0000x reference)
//
#include <hip/hip_runtime.h>

// LaplacianLoss on a fixed 512x512 grid mesh, B=32.
// Lv[b,v] = verts[b,v] - (1/deg[v]) * sum_{nbr} verts[b,nbr]
// neighbors: (i,j+-1), (i+-1,j), (i-1,j+1), (i+1,j-1)   [anti-diagonal triangulation]
// out = mean over (B,V) of |Lv|^2  (scalar f32)

#define GH 512
#define GW 512
#define GV (GH * GW)

__global__ __launch_bounds__(256) void lap_loss_kernel(
    const float* __restrict__ verts, float* __restrict__ out, int B) {
    const long long idx = (long long)blockIdx.x * blockDim.x + threadIdx.x;
    const long long total = (long long)B * GV;

    float local = 0.0f;
    if (idx < total) {
        const int b = (int)(idx >> 18);          // V = 2^18
        const int v = (int)(idx & (GV - 1));
        const int i = v >> 9;                    // W = 2^9
        const int j = v & (GW - 1);
        const float* __restrict__ base = verts + (long long)b * GV * 3;

        float sx = 0.f, sy = 0.f, sz = 0.f;
        int deg = 0;

        // accumulate neighbor coords
        #define ACC(vv) { const float* p = base + (long long)(vv) * 3; \
                          sx += p[0]; sy += p[1]; sz += p[2]; deg++; }
        if (j > 0)                  ACC(v - 1);
        if (j < GW - 1)             ACC(v + 1);
        if (i > 0)                  ACC(v - GW);
        if (i < GH - 1)             ACC(v + GW);
        if (i > 0 && j < GW - 1)    ACC(v - GW + 1);   // anti-diag up-right
        if (i < GH - 1 && j > 0)    ACC(v + GW - 1);   // anti-diag down-left
        #undef ACC

        const float inv = -1.0f / (float)deg;
        const float* p = base + (long long)v * 3;
        const float lx = p[0] + inv * sx;
        const float ly = p[1] + inv * sy;
        const float lz = p[2] + inv * sz;
        local = lx * lx + ly * ly + lz * lz;
    }

    // wave-64 shuffle reduction
    #pragma unroll
    for (int off = 32; off > 0; off >>= 1)
        local += __shfl_down(local, off, 64);

    __shared__ float wsum[4];                    // 256 threads / 64 lanes
    const int lane = threadIdx.x & 63;
    const int wid  = threadIdx.x >> 6;
    if (lane == 0) wsum[wid] = local;
    __syncthreads();

    if (threadIdx.x == 0) {
        const float s = wsum[0] + wsum[1] + wsum[2] + wsum[3];
        const float scale = 1.0f / ((float)B * (float)GV);
        atomicAdd(out, s * scale);               // device-scope by default on CDNA
    }
}

extern "C" void kernel_launch(void* const* d_in, const int* in_sizes, int n_in,
                              void* d_out, int out_size, void* d_ws, size_t ws_size,
                              hipStream_t stream) {
    const float* verts = (const float*)d_in[0];
    float* out = (float*)d_out;

    const int B = in_sizes[0] / (GV * 3);        // 32

    // d_out is re-poisoned to 0xAA before every timed replay -> zero it here.
    hipMemsetAsync(out, 0, sizeof(float), stream);

    const long long total = (long long)B * GV;   // 8,388,608
    const int block = 256;
    const int grid = (int)((total + block - 1) / block);  // 32768
    lap_loss_kernel<<<grid, block, 0, stream>>>(verts, out, B);
}

// Round 2
// 191.335 us; speedup vs baseline: 2.8545x; 2.8545x over previous
//
#include <hip/hip_runtime.h>

// LaplacianLoss on a fixed 512x512 grid mesh, B=32.
// Lv[b,v] = verts[b,v] - (1/deg[v]) * sum_{nbr} verts[b,nbr]
// neighbors: (i,j+-1), (i+-1,j), (i-1,j+1), (i+1,j-1)   [anti-diagonal triangulation]
// out = mean over (B,V) of |Lv|^2  (scalar f32)
//
// R1 lesson: 32768 same-address fp atomics serialized (~330us). Two-stage
// reduction with per-block partials in d_ws instead; no atomics at all.

#define GH 512
#define GW 512
#define GV (GH * GW)
#define NBLK 4096

__global__ __launch_bounds__(256) void lap_partial_kernel(
    const float* __restrict__ verts, float* __restrict__ partials, int B) {
    const long long total = (long long)B * GV;
    const long long nthreads = (long long)gridDim.x * blockDim.x;
    const long long tid0 = (long long)blockIdx.x * blockDim.x + threadIdx.x;

    float local = 0.0f;
    for (long long idx = tid0; idx < total; idx += nthreads) {
        const int b = (int)(idx >> 18);          // V = 2^18
        const int v = (int)(idx & (GV - 1));
        const int i = v >> 9;                    // W = 2^9
        const int j = v & (GW - 1);
        const float* __restrict__ base = verts + (long long)b * GV * 3;

        float sx = 0.f, sy = 0.f, sz = 0.f;
        int deg = 0;

        #define ACC(vv) { const float* p = base + (long long)(vv) * 3; \
                          sx += p[0]; sy += p[1]; sz += p[2]; deg++; }
        if (j > 0)                  ACC(v - 1);
        if (j < GW - 1)             ACC(v + 1);
        if (i > 0)                  ACC(v - GW);
        if (i < GH - 1)             ACC(v + GW);
        if (i > 0 && j < GW - 1)    ACC(v - GW + 1);   // anti-diag up-right
        if (i < GH - 1 && j > 0)    ACC(v + GW - 1);   // anti-diag down-left
        #undef ACC

        const float inv = -1.0f / (float)deg;
        const float* p = base + (long long)v * 3;
        const float lx = fmaf(inv, sx, p[0]);
        const float ly = fmaf(inv, sy, p[1]);
        const float lz = fmaf(inv, sz, p[2]);
        local += lx * lx + ly * ly + lz * lz;
    }

    // wave-64 shuffle reduction
    #pragma unroll
    for (int off = 32; off > 0; off >>= 1)
        local += __shfl_down(local, off, 64);

    __shared__ float wsum[4];                    // 256 threads / 64 lanes
    const int lane = threadIdx.x & 63;
    const int wid  = threadIdx.x >> 6;
    if (lane == 0) wsum[wid] = local;
    __syncthreads();

    if (threadIdx.x == 0)
        partials[blockIdx.x] = wsum[0] + wsum[1] + wsum[2] + wsum[3];
}

__global__ __launch_bounds__(256) void lap_final_kernel(
    const float* __restrict__ partials, float* __restrict__ out, int nblk, int B) {
    float local = 0.0f;
    for (int k = threadIdx.x; k < nblk; k += 256)
        local += partials[k];

    #pragma unroll
    for (int off = 32; off > 0; off >>= 1)
        local += __shfl_down(local, off, 64);

    __shared__ float wsum[4];
    const int lane = threadIdx.x & 63;
    const int wid  = threadIdx.x >> 6;
    if (lane == 0) wsum[wid] = local;
    __syncthreads();

    if (threadIdx.x == 0) {
        const float s = wsum[0] + wsum[1] + wsum[2] + wsum[3];
        out[0] = s / ((float)B * (float)GV);
    }
}

extern "C" void kernel_launch(void* const* d_in, const int* in_sizes, int n_in,
                              void* d_out, int out_size, void* d_ws, size_t ws_size,
                              hipStream_t stream) {
    const float* verts = (const float*)d_in[0];
    float* out = (float*)d_out;
    float* partials = (float*)d_ws;               // NBLK floats = 16 KB

    const int B = in_sizes[0] / (GV * 3);         // 32

    lap_partial_kernel<<<NBLK, 256, 0, stream>>>(verts, partials, B);
    lap_final_kernel<<<1, 256, 0, stream>>>(partials, out, NBLK, B);
}

// Round 3
// 179.884 us; speedup vs baseline: 3.0362x; 1.0637x over previous
//
#include <hip/hip_runtime.h>

// LaplacianLoss on a fixed 512x512 grid mesh, B=32.
// Lv[b,(i,j)] = v - (1/deg)*sum(nbrs), nbrs = (i,j+-1),(i+-1,j),(i-1,j+1),(i+1,j-1)
// out = mean over (B,V) of |Lv|^2.
//
// R2 lesson: 21 scalar gathers/vertex made the kernel load-issue/latency bound
// (2.3 TB/s, VALU 26%). R3: register-rolling column stencil — each lane owns a
// column, loads its own vertex once (3 dwords = ideal traffic), neighbors via
// wave shuffles; 2-row software pipeline to hide HBM latency.

#define GH 512
#define GW 512
#define GV (GH * GW)
#define RI 16
#define NCHUNK (GH / RI)          // 32 row-chunks

struct Row9 { float x, y, z, xm, ym, zm, xp, yp, zp; };

__global__ __launch_bounds__(256) void lap_partial_kernel(
    const float* __restrict__ verts, float* __restrict__ partials) {
    const int bid   = blockIdx.x;
    const int chunk = bid & (NCHUNK - 1);
    const int half  = (bid >> 5) & 1;
    const int b     = bid >> 6;
    const int lane  = threadIdx.x & 63;
    const int wave  = threadIdx.x >> 6;
    const int j     = half * 256 + wave * 64 + lane;   // owned column
    const int i0    = chunk * RI;
    const float* __restrict__ base = verts + (size_t)b * (GV * 3);

    // -1/deg for the three i-regimes (j-dependence precomputed per lane)
    const int jl = (j > 0), jr = (j < GW - 1);
    const float inv_int = -1.0f / (float)(2 + 2 * jl + 2 * jr);
    const float inv_top = -1.0f / (float)(1 + 2 * jl + jr);
    const float inv_bot = -1.0f / (float)(1 + jl + 2 * jr);

    // pipeline state: rawA = row loaded last iter, rawB = two iters ago
    Row9 rawA = {}, rawB = {};
    // triples: t = top row (needs j, j+1), m = mid/center row (needs j-1,j,j+1)
    float t_x = 0, t_xp = 0, t_y = 0, t_yp = 0, t_z = 0, t_zp = 0;
    float m_xm = 0, m_x = 0, m_xp = 0, m_ym = 0, m_y = 0, m_yp = 0,
          m_zm = 0, m_z = 0, m_zp = 0;
    float local = 0.0f;

    #pragma unroll
    for (int k = 0; k < RI + 4; ++k) {
        // ---- stage 1: issue loads for row r = i0-1+k (consumed at k+2) ----
        Row9 rawN = {};
        if (k <= RI + 1) {
            const int r = i0 - 1 + k;
            if (r >= 0 && r < GH) {
                const float* p = base + (size_t)(r * GW + j) * 3;
                rawN.x = p[0]; rawN.y = p[1]; rawN.z = p[2];
                if (lane == 0 && j > 0) {           // wave-left halo column
                    rawN.xm = p[-3]; rawN.ym = p[-2]; rawN.zm = p[-1];
                }
                if (lane == 63 && j < GW - 1) {     // wave-right halo column
                    rawN.xp = p[3]; rawN.yp = p[4]; rawN.zp = p[5];
                }
            }
        }

        // ---- stage 2: build bottom triple from rawB (loaded 2 iters ago) ----
        float b_xm = 0, b_x = 0, b_xp = 0, b_ym = 0, b_y = 0, b_yp = 0,
              b_zm = 0, b_z = 0, b_zp = 0;
        if (k >= 2) {
            b_x = rawB.x; b_y = rawB.y; b_z = rawB.z;
            const float sxm = __shfl_up(rawB.x, 1, 64);
            const float sym = __shfl_up(rawB.y, 1, 64);
            const float szm = __shfl_up(rawB.z, 1, 64);
            const float sxp = __shfl_down(rawB.x, 1, 64);
            const float syp = __shfl_down(rawB.y, 1, 64);
            const float szp = __shfl_down(rawB.z, 1, 64);
            b_xm = (lane == 0)  ? rawB.xm : sxm;
            b_ym = (lane == 0)  ? rawB.ym : sym;
            b_zm = (lane == 0)  ? rawB.zm : szm;
            b_xp = (lane == 63) ? rawB.xp : sxp;
            b_yp = (lane == 63) ? rawB.yp : syp;
            b_zp = (lane == 63) ? rawB.zp : szp;
        }

        // ---- stage 3: compute center row ci = i0+k-4 using (t, m, b) ----
        if (k >= 4) {
            const int ci = i0 + k - 4;              // in [i0, i0+RI-1]
            float inv = inv_int;
            if (ci == 0) inv = inv_top;
            else if (ci == GH - 1) inv = inv_bot;
            float sx = m_xm + m_xp, sy = m_ym + m_yp, sz = m_zm + m_zp;
            if (ci > 0)      { sx += t_x + t_xp; sy += t_y + t_yp; sz += t_z + t_zp; }
            if (ci < GH - 1) { sx += b_x + b_xm; sy += b_y + b_ym; sz += b_z + b_zm; }
            const float lx = fmaf(inv, sx, m_x);
            const float ly = fmaf(inv, sy, m_y);
            const float lz = fmaf(inv, sz, m_z);
            local = fmaf(lx, lx, local);
            local = fmaf(ly, ly, local);
            local = fmaf(lz, lz, local);
        }

        // ---- rotate pipeline ----
        t_x = m_x; t_xp = m_xp; t_y = m_y; t_yp = m_yp; t_z = m_z; t_zp = m_zp;
        m_xm = b_xm; m_x = b_x; m_xp = b_xp;
        m_ym = b_ym; m_y = b_y; m_yp = b_yp;
        m_zm = b_zm; m_z = b_z; m_zp = b_zp;
        rawB = rawA; rawA = rawN;
    }

    // ---- block reduction (wave shuffle -> LDS -> one store) ----
    #pragma unroll
    for (int off = 32; off > 0; off >>= 1)
        local += __shfl_down(local, off, 64);

    __shared__ float wsum[4];
    if (lane == 0) wsum[wave] = local;
    __syncthreads();
    if (threadIdx.x == 0)
        partials[blockIdx.x] = wsum[0] + wsum[1] + wsum[2] + wsum[3];
}

__global__ __launch_bounds__(256) void lap_final_kernel(
    const float* __restrict__ partials, float* __restrict__ out, int nblk, int B) {
    float local = 0.0f;
    for (int k = threadIdx.x; k < nblk; k += 256)
        local += partials[k];

    #pragma unroll
    for (int off = 32; off > 0; off >>= 1)
        local += __shfl_down(local, off, 64);

    __shared__ float wsum[4];
    const int lane = threadIdx.x & 63;
    const int wid  = threadIdx.x >> 6;
    if (lane == 0) wsum[wid] = local;
    __syncthreads();

    if (threadIdx.x == 0) {
        const float s = wsum[0] + wsum[1] + wsum[2] + wsum[3];
        out[0] = s / ((float)B * (float)GV);
    }
}

extern "C" void kernel_launch(void* const* d_in, const int* in_sizes, int n_in,
                              void* d_out, int out_size, void* d_ws, size_t ws_size,
                              hipStream_t stream) {
    const float* verts = (const float*)d_in[0];
    float* out = (float*)d_out;
    float* partials = (float*)d_ws;

    const int B = in_sizes[0] / (GV * 3);          // 32
    const int nblk = B * 2 * NCHUNK;               // 2048 blocks

    lap_partial_kernel<<<nblk, 256, 0, stream>>>(verts, partials);
    lap_final_kernel<<<1, 256, 0, stream>>>(partials, out, nblk, B);
}

// Round 4
// 162.110 us; speedup vs baseline: 3.3691x; 1.1096x over previous
//
#include <hip/hip_runtime.h>

// LaplacianLoss on a fixed 512x512 grid mesh, B=32.
// Lv[b,(i,j)] = v - (1/deg)*sum(nbrs), nbrs = (i,j+-1),(i+-1,j),(i-1,j+1),(i+1,j-1)
// out = mean over (B,V) of |Lv|^2.
//
// R3 lesson: shuffle pipeline -> VGPR=128, occupancy 20%, latency-bound.
// R4: rolling column walk, but l/c/r come from direct loads (L1 absorbs the 3x
// overlap); each loaded row is immediately reduced to T/B/M/C contributions so
// carried state is only 21 floats. Target VGPR<=64 -> 8 waves/SIMD.

#define GH 512
#define GW 512
#define GV (GH * GW)
#define RI 16
#define NCHUNK (GH / RI)          // 32 row-chunks

struct F3 { float x, y, z; };

__global__ __launch_bounds__(256) void lap_partial_kernel(
    const float* __restrict__ verts, float* __restrict__ partials) {
    const int bid   = blockIdx.x;
    const int chunk = bid & (NCHUNK - 1);
    const int half  = (bid >> 5) & 1;
    const int b     = bid >> 6;
    const int j     = half * 256 + (int)threadIdx.x;   // owned column
    const int i0    = chunk * RI;
    const float* __restrict__ base = verts + (size_t)b * (GV * 3);

    const int jl = (j > 0), jr = (j < GW - 1);
    const float fl = (float)jl, fr = (float)jr;        // edge masks
    const float inv_int = -1.0f / (float)(2 + 2 * jl + 2 * jr);
    const float inv_top = -1.0f / (float)(1 + 2 * jl + jr);
    const float inv_bot = -1.0f / (float)(1 + jl + 2 * jr);

    // clamped column float-offsets within a row (edge values masked to 0 later)
    const int cl = 3 * (jl ? j - 1 : 0);
    const int cc = 3 * j;
    const int cr = 3 * (jr ? j + 1 : GW - 1);

    F3 pL = {}, pC = {}, pR = {};   // loads issued previous iter (row i0-2+k)
    F3 T2 = {}, T1 = {};            // T carried 2 / 1 iters back
    F3 M1 = {}, C1 = {};            // M, C carried 1 iter back
    float local = 0.0f;

    #pragma unroll
    for (int k = 0; k <= RI + 2; ++k) {
        // ---- a) issue loads for row rload = i0-1+k (block-uniform branch) ----
        F3 qL = {}, qC = {}, qR = {};
        const int rload = i0 - 1 + k;
        if (k <= RI + 1 && rload >= 0 && rload < GH) {
            const float* __restrict__ rp = base + (size_t)rload * (GW * 3);
            qL.x = rp[cl]; qL.y = rp[cl + 1]; qL.z = rp[cl + 2];
            qC.x = rp[cc]; qC.y = rp[cc + 1]; qC.z = rp[cc + 2];
            qR.x = rp[cr]; qR.y = rp[cr + 1]; qR.z = rp[cr + 2];
        }

        // ---- b) process row i0+k-2: reduce raw to B (used now), T/M/C (later) ----
        const F3 Lm = { fl * pL.x, fl * pL.y, fl * pL.z };
        const F3 Rm = { fr * pR.x, fr * pR.y, fr * pR.z };
        const F3 Bx = { pC.x + Lm.x, pC.y + Lm.y, pC.z + Lm.z };
        const F3 Tn = { pC.x + Rm.x, pC.y + Rm.y, pC.z + Rm.z };
        const F3 Mn = { Lm.x + Rm.x, Lm.y + Rm.y, Lm.z + Rm.z };
        const F3 Cn = pC;

        // ---- c) finalize center c = i0+k-3 using T2(c-1), M1/C1(c), Bx(c+1) ----
        if (k >= 3) {
            const int c = i0 + k - 3;
            const float inv = (c == 0) ? inv_top
                            : ((c == GH - 1) ? inv_bot : inv_int);
            const float sx = T2.x + M1.x + Bx.x;
            const float sy = T2.y + M1.y + Bx.y;
            const float sz = T2.z + M1.z + Bx.z;
            const float lx = fmaf(inv, sx, C1.x);
            const float ly = fmaf(inv, sy, C1.y);
            const float lz = fmaf(inv, sz, C1.z);
            local = fmaf(lx, lx, local);
            local = fmaf(ly, ly, local);
            local = fmaf(lz, lz, local);
        }

        // ---- d) rotate pipeline ----
        T2 = T1; T1 = Tn; M1 = Mn; C1 = Cn;
        pL = qL; pC = qC; pR = qR;
    }

    // ---- block reduction (wave shuffle -> LDS -> one store) ----
    #pragma unroll
    for (int off = 32; off > 0; off >>= 1)
        local += __shfl_down(local, off, 64);

    __shared__ float wsum[4];
    const int lane = threadIdx.x & 63;
    const int wave = threadIdx.x >> 6;
    if (lane == 0) wsum[wave] = local;
    __syncthreads();
    if (threadIdx.x == 0)
        partials[blockIdx.x] = wsum[0] + wsum[1] + wsum[2] + wsum[3];
}

__global__ __launch_bounds__(256) void lap_final_kernel(
    const float* __restrict__ partials, float* __restrict__ out, int nblk, int B) {
    float local = 0.0f;
    for (int k = threadIdx.x; k < nblk; k += 256)
        local += partials[k];

    #pragma unroll
    for (int off = 32; off > 0; off >>= 1)
        local += __shfl_down(local, off, 64);

    __shared__ float wsum[4];
    const int lane = threadIdx.x & 63;
    const int wid  = threadIdx.x >> 6;
    if (lane == 0) wsum[wid] = local;
    __syncthreads();

    if (threadIdx.x == 0) {
        const float s = wsum[0] + wsum[1] + wsum[2] + wsum[3];
        out[0] = s / ((float)B * (float)GV);
    }
}

extern "C" void kernel_launch(void* const* d_in, const int* in_sizes, int n_in,
                              void* d_out, int out_size, void* d_ws, size_t ws_size,
                              hipStream_t stream) {
    const float* verts = (const float*)d_in[0];
    float* out = (float*)d_out;
    float* partials = (float*)d_ws;

    const int B = in_sizes[0] / (GV * 3);          // 32
    const int nblk = B * 2 * NCHUNK;               // 2048 blocks

    lap_partial_kernel<<<nblk, 256, 0, stream>>>(verts, partials);
    lap_final_kernel<<<1, 256, 0, stream>>>(partials, out, nblk, B);
}